// Round 1
// baseline (2381.346 us; speedup 1.0000x reference)
//
#include <hip/hip_runtime.h>
#include <hip/hip_bf16.h>

#define SEQ 4096
#define DIM 256
#define BATCH 4
#define LAYERS 4

typedef __attribute__((ext_vector_type(8))) short bf16x8;
typedef __attribute__((ext_vector_type(4))) float f32x4;

__device__ __forceinline__ unsigned short f2bf(float f) {
    union { float f; unsigned u; } v; v.f = f;
    unsigned r = v.u + 0x7fff + ((v.u >> 16) & 1);   // round-to-nearest-even
    return (unsigned short)(r >> 16);
}

// ---------------- fp32 -> bf16 conversion (vectorized) ----------------
__global__ __launch_bounds__(256) void cvt_kernel(const float* __restrict__ in,
                                                  unsigned short* __restrict__ out,
                                                  int n) {
    int i = (blockIdx.x * blockDim.x + threadIdx.x) * 4;
    if (i + 3 < n) {
        float4 v = *(const float4*)(in + i);
        unsigned short o0 = f2bf(v.x), o1 = f2bf(v.y), o2 = f2bf(v.z), o3 = f2bf(v.w);
        ushort4 o = {o0, o1, o2, o3};
        *(ushort4*)(out + i) = o;
    }
}

// ---------------- projection GEMM: out = x @ W^T + b (bf16 MFMA) ----------------
// x: [16384,256] bf16, W: [256,256] bf16 (row = output dim), bias fp32.
// vt_mode==0: out[m*256+n] bf16 ; vt_mode==1: out[(b*DIM+n)*SEQ + s] (V transposed)
__global__ __launch_bounds__(256) void proj_kernel(const unsigned short* __restrict__ xb,
                                                   const unsigned short* __restrict__ Wb,
                                                   const float* __restrict__ bias,
                                                   unsigned short* __restrict__ out,
                                                   int vt_mode) {
    int lane = threadIdx.x & 63;
    int wid  = threadIdx.x >> 6;
    int c = lane & 15, g = lane >> 4;
    int m0 = blockIdx.x * 64 + wid * 16;
    int n0 = blockIdx.y * 64;

    f32x4 acc[4] = {};
    const unsigned short* xrow = xb + (size_t)(m0 + c) * DIM + g * 8;

    #pragma unroll
    for (int s = 0; s < 8; ++s) {
        bf16x8 a = *(const bf16x8*)(xrow + s * 32);
        #pragma unroll
        for (int nt = 0; nt < 4; ++nt) {
            const unsigned short* wp = Wb + (size_t)(n0 + nt * 16 + c) * DIM + s * 32 + g * 8;
            bf16x8 bf = *(const bf16x8*)wp;
            acc[nt] = __builtin_amdgcn_mfma_f32_16x16x32_bf16(a, bf, acc[nt], 0, 0, 0);
        }
    }

    #pragma unroll
    for (int nt = 0; nt < 4; ++nt) {
        int col = n0 + nt * 16 + c;
        float bv = bias[col];
        #pragma unroll
        for (int i = 0; i < 4; ++i) {
            int row = m0 + g * 4 + i;
            unsigned short h = f2bf(acc[nt][i] + bv);
            if (!vt_mode) {
                out[(size_t)row * DIM + col] = h;
            } else {
                int b = row >> 12;            // row / SEQ
                int sidx = row & (SEQ - 1);
                out[((size_t)b * DIM + col) * SEQ + sidx] = h;
            }
        }
    }
}

// ---------------- causal flash attention + residual ----------------
// qb,kb: [B][S][D] bf16 ; vt: [B][D][S] bf16 ; xres/xout: [B][S][D] fp32
__global__ __launch_bounds__(256) void attn_kernel(const unsigned short* __restrict__ qb,
                                                   const unsigned short* __restrict__ kb,
                                                   const unsigned short* __restrict__ vt,
                                                   const float* __restrict__ xres,
                                                   float* __restrict__ xout) {
    __shared__ unsigned short Plds[4][16][32];   // per-wave P tile

    int lane = threadIdx.x & 63;
    int wid  = threadIdx.x >> 6;
    int c = lane & 15, g = lane >> 4;
    int qtile = blockIdx.x * 4 + wid;     // 0..255
    int b = blockIdx.y;
    int q0 = qtile * 16;

    // hoist Q fragments: q[q0+c][32*s + 8*g + j]
    bf16x8 qf[8];
    const unsigned short* qp = qb + ((size_t)(b * SEQ + q0 + c)) * DIM + g * 8;
    #pragma unroll
    for (int s = 0; s < 8; ++s) qf[s] = *(const bf16x8*)(qp + s * 32);

    f32x4 o[16] = {};            // o[dt][i]: O[q0+4g+i][16*dt+c]
    float m_run[4], l_run[4];
    #pragma unroll
    for (int i = 0; i < 4; ++i) { m_run[i] = -1e30f; l_run[i] = 0.f; }

    const float kscale = (1.0f / 16.0f) * 1.44269504f;   // 1/sqrt(D) * log2(e)

    int nsteps = (q0 + 16 + 31) >> 5;
    const unsigned short* kbase = kb + (size_t)b * SEQ * DIM;
    const unsigned short* vbase = vt + (size_t)b * DIM * SEQ;

    for (int st = 0; st < nsteps; ++st) {
        int k0 = st * 32;

        // ---- scores S[16q][32k] = Q K^T ----
        f32x4 sa[2] = {};
        #pragma unroll
        for (int t = 0; t < 2; ++t) {
            const unsigned short* kp = kbase + (size_t)(k0 + t * 16 + c) * DIM + g * 8;
            #pragma unroll
            for (int s = 0; s < 8; ++s) {
                bf16x8 kf = *(const bf16x8*)(kp + s * 32);
                sa[t] = __builtin_amdgcn_mfma_f32_16x16x32_bf16(qf[s], kf, sa[t], 0, 0, 0);
            }
        }

        // ---- mask + scale + online softmax ----
        float sv[2][4];
        #pragma unroll
        for (int i = 0; i < 4; ++i) {
            int qrow = q0 + g * 4 + i;
            #pragma unroll
            for (int t = 0; t < 2; ++t) {
                int key = k0 + t * 16 + c;
                float s = sa[t][i] * kscale;
                sv[t][i] = (key <= qrow) ? s : -1e30f;
            }
            float mv = fmaxf(sv[0][i], sv[1][i]);
            mv = fmaxf(mv, __shfl_xor(mv, 1));
            mv = fmaxf(mv, __shfl_xor(mv, 2));
            mv = fmaxf(mv, __shfl_xor(mv, 4));
            mv = fmaxf(mv, __shfl_xor(mv, 8));

            float mnew = fmaxf(m_run[i], mv);
            float corr = exp2f(m_run[i] - mnew);
            m_run[i] = mnew;
            float p0 = exp2f(sv[0][i] - mnew);
            float p1 = exp2f(sv[1][i] - mnew);
            float ps = p0 + p1;
            ps += __shfl_xor(ps, 1);
            ps += __shfl_xor(ps, 2);
            ps += __shfl_xor(ps, 4);
            ps += __shfl_xor(ps, 8);
            l_run[i] = l_run[i] * corr + ps;
            #pragma unroll
            for (int dt = 0; dt < 16; ++dt) o[dt][i] *= corr;

            Plds[wid][g * 4 + i][c]      = f2bf(p0);
            Plds[wid][g * 4 + i][16 + c] = f2bf(p1);
        }

        // ---- P re-layout: A-fragment read (row = c, k = 8g..8g+7) ----
        bf16x8 pa = *(const bf16x8*)&Plds[wid][c][g * 8];

        // ---- O += P V : V B-frag from transposed vt (contiguous ushort8) ----
        #pragma unroll
        for (int dt = 0; dt < 16; ++dt) {
            const unsigned short* vp = vbase + (size_t)(dt * 16 + c) * SEQ + k0 + g * 8;
            bf16x8 vf = *(const bf16x8*)vp;
            o[dt] = __builtin_amdgcn_mfma_f32_16x16x32_bf16(pa, vf, o[dt], 0, 0, 0);
        }
    }

    // ---- epilogue: divide by l, add residual, store fp32 ----
    #pragma unroll
    for (int i = 0; i < 4; ++i) {
        float inv = 1.0f / l_run[i];
        int row = q0 + g * 4 + i;
        #pragma unroll
        for (int dt = 0; dt < 16; ++dt) {
            int col = dt * 16 + c;
            size_t idx = ((size_t)b * SEQ + row) * DIM + col;
            xout[idx] = o[dt][i] * inv + xres[idx];
        }
    }
}

// ---------------- launch ----------------
extern "C" void kernel_launch(void* const* d_in, const int* in_sizes, int n_in,
                              void* d_out, int out_size, void* d_ws, size_t ws_size,
                              hipStream_t stream) {
    const float* x_in = (const float*)d_in[0];
    const float* Wq   = (const float*)d_in[1];
    const float* bq   = (const float*)d_in[2];
    const float* Wk   = (const float*)d_in[3];
    const float* bk   = (const float*)d_in[4];
    const float* Wv   = (const float*)d_in[5];
    const float* bv   = (const float*)d_in[6];
    float* xout = (float*)d_out;

    const size_t SD = (size_t)BATCH * SEQ * DIM;      // 4.19M elems
    const size_t WL = (size_t)LAYERS * DIM * DIM;     // 262144 elems
    unsigned short* qb  = (unsigned short*)d_ws;
    unsigned short* kbf = qb  + SD;
    unsigned short* vt  = kbf + SD;
    unsigned short* xb  = vt  + SD;
    unsigned short* Wqb = xb  + SD;
    unsigned short* Wkb = Wqb + WL;
    unsigned short* Wvb = Wkb + WL;
    // total ws: (4*SD + 3*WL)*2 bytes ~= 35 MB

    // convert all weights once
    {
        int n = (int)WL;
        int blocks = (n / 4 + 255) / 256;
        cvt_kernel<<<blocks, 256, 0, stream>>>(Wq, Wqb, n);
        cvt_kernel<<<blocks, 256, 0, stream>>>(Wk, Wkb, n);
        cvt_kernel<<<blocks, 256, 0, stream>>>(Wv, Wvb, n);
    }

    dim3 pgrid(BATCH * SEQ / 64, DIM / 64), pblk(256);
    dim3 agrid(SEQ / 64, BATCH), ablk(256);

    for (int l = 0; l < LAYERS; ++l) {
        const float* xcur = (l == 0) ? x_in : xout;
        // x -> bf16
        {
            int n = (int)SD;
            int blocks = (n / 4 + 255) / 256;
            cvt_kernel<<<blocks, 256, 0, stream>>>(xcur, xb, n);
        }
        proj_kernel<<<pgrid, pblk, 0, stream>>>(xb, Wqb + (size_t)l * DIM * DIM, bq + l * DIM, qb, 0);
        proj_kernel<<<pgrid, pblk, 0, stream>>>(xb, Wkb + (size_t)l * DIM * DIM, bk + l * DIM, kbf, 0);
        proj_kernel<<<pgrid, pblk, 0, stream>>>(xb, Wvb + (size_t)l * DIM * DIM, bv + l * DIM, vt, 1);
        attn_kernel<<<agrid, ablk, 0, stream>>>(qb, kbf, vt, xcur, xout);
    }
}

// Round 2
// 1583.754 us; speedup vs baseline: 1.5036x; 1.5036x over previous
//
#include <hip/hip_runtime.h>
#include <hip/hip_bf16.h>

#define SEQ 4096
#define DIM 256
#define BATCH 4
#define LAYERS 4
#define QT (SEQ / 16)        // 256 q-tiles per batch
#define PB (BATCH * QT)      // 1024 q-tiles total

typedef __attribute__((ext_vector_type(8))) short bf16x8;
typedef __attribute__((ext_vector_type(4))) float f32x4;

__device__ __forceinline__ unsigned short f2bf(float f) {
    union { float f; unsigned u; } v; v.f = f;
    unsigned r = v.u + 0x7fff + ((v.u >> 16) & 1);   // round-to-nearest-even
    return (unsigned short)(r >> 16);
}

// ---------------- fp32 -> bf16 conversion (vectorized) ----------------
__global__ __launch_bounds__(256) void cvt_kernel(const float* __restrict__ in,
                                                  unsigned short* __restrict__ out,
                                                  int n) {
    int i = (blockIdx.x * blockDim.x + threadIdx.x) * 4;
    if (i + 3 < n) {
        float4 v = *(const float4*)(in + i);
        ushort4 o = {f2bf(v.x), f2bf(v.y), f2bf(v.z), f2bf(v.w)};
        *(ushort4*)(out + i) = o;
    }
}

// ---------------- fused QKV projection: out_z = x @ W_z^T + b_z ----------------
// blockIdx.z selects q/k/v. V (z==2) is stored transposed: vt[(b*DIM+n)*SEQ + s].
__global__ __launch_bounds__(256) void projqkv_kernel(const unsigned short* __restrict__ xb,
                                                      const unsigned short* __restrict__ Wq,
                                                      const unsigned short* __restrict__ Wk,
                                                      const unsigned short* __restrict__ Wv,
                                                      const float* __restrict__ bq,
                                                      const float* __restrict__ bk,
                                                      const float* __restrict__ bv,
                                                      unsigned short* __restrict__ outq,
                                                      unsigned short* __restrict__ outk,
                                                      unsigned short* __restrict__ outv) {
    int z = blockIdx.z;
    const unsigned short* Wb = (z == 0) ? Wq : (z == 1) ? Wk : Wv;
    const float* bias        = (z == 0) ? bq : (z == 1) ? bk : bv;
    unsigned short* out      = (z == 0) ? outq : (z == 1) ? outk : outv;
    int vt_mode = (z == 2);

    int lane = threadIdx.x & 63;
    int wid  = threadIdx.x >> 6;
    int c = lane & 15, g = lane >> 4;
    int m0 = blockIdx.x * 64 + wid * 16;
    int n0 = blockIdx.y * 64;

    f32x4 acc[4] = {};
    const unsigned short* xrow = xb + (size_t)(m0 + c) * DIM + g * 8;

    #pragma unroll
    for (int s = 0; s < 8; ++s) {
        bf16x8 a = *(const bf16x8*)(xrow + s * 32);
        #pragma unroll
        for (int nt = 0; nt < 4; ++nt) {
            const unsigned short* wp = Wb + (size_t)(n0 + nt * 16 + c) * DIM + s * 32 + g * 8;
            bf16x8 bf = *(const bf16x8*)wp;
            acc[nt] = __builtin_amdgcn_mfma_f32_16x16x32_bf16(a, bf, acc[nt], 0, 0, 0);
        }
    }

    #pragma unroll
    for (int nt = 0; nt < 4; ++nt) {
        int col = n0 + nt * 16 + c;
        float bv_ = bias[col];
        #pragma unroll
        for (int i = 0; i < 4; ++i) {
            int row = m0 + g * 4 + i;
            unsigned short h = f2bf(acc[nt][i] + bv_);
            if (!vt_mode) {
                out[(size_t)row * DIM + col] = h;
            } else {
                int b = row >> 12;
                int sidx = row & (SEQ - 1);
                out[((size_t)b * DIM + col) * SEQ + sidx] = h;
            }
        }
    }
}

// ---------------- causal flash attention (split-KV) ----------------
// qb,kb: [B][S][D] bf16 ; vt: [B][D][S] bf16
// split==1: writes xout = O/l + xres (fp32) and xb_next (bf16) directly.
// split>1 : writes unnormalized partials (partO fp32, partM/partL per row).
__global__ __launch_bounds__(256) void attn_kernel(const unsigned short* __restrict__ qb,
                                                   const unsigned short* __restrict__ kb,
                                                   const unsigned short* __restrict__ vt,
                                                   const float* __restrict__ xres,
                                                   float* __restrict__ xout,
                                                   unsigned short* __restrict__ xb_next,
                                                   float* __restrict__ partO,
                                                   float* __restrict__ partM,
                                                   float* __restrict__ partL,
                                                   int split) {
    __shared__ unsigned short Plds[4][16][32];

    int lane = threadIdx.x & 63;
    int wid  = threadIdx.x >> 6;
    int c = lane & 15, g = lane >> 4;
    int qtile = blockIdx.x + wid * 64;      // balanced: each block mixes short+long tiles
    int s_idx = blockIdx.y;
    int b = blockIdx.z;
    int q0 = qtile * 16;

    bf16x8 qf[8];
    const unsigned short* qp = qb + ((size_t)(b * SEQ + q0 + c)) * DIM + g * 8;
    #pragma unroll
    for (int s = 0; s < 8; ++s) qf[s] = *(const bf16x8*)(qp + s * 32);

    f32x4 o[16] = {};
    float m_run[4], l_run[4];
    #pragma unroll
    for (int i = 0; i < 4; ++i) { m_run[i] = -1e30f; l_run[i] = 0.f; }

    const float kscale = (1.0f / 16.0f) * 1.44269504f;   // 1/sqrt(D) * log2(e)

    int nsteps = (q0 + 16 + 31) >> 5;
    const unsigned short* kbase = kb + (size_t)b * SEQ * DIM;
    const unsigned short* vbase = vt + (size_t)b * DIM * SEQ;

    for (int st = s_idx; st < nsteps; st += split) {
        int k0 = st * 32;

        f32x4 sa[2] = {};
        #pragma unroll
        for (int t = 0; t < 2; ++t) {
            const unsigned short* kp = kbase + (size_t)(k0 + t * 16 + c) * DIM + g * 8;
            #pragma unroll
            for (int s = 0; s < 8; ++s) {
                bf16x8 kf = *(const bf16x8*)(kp + s * 32);
                sa[t] = __builtin_amdgcn_mfma_f32_16x16x32_bf16(qf[s], kf, sa[t], 0, 0, 0);
            }
        }

        float sv[2][4];
        #pragma unroll
        for (int i = 0; i < 4; ++i) {
            int qrow = q0 + g * 4 + i;
            #pragma unroll
            for (int t = 0; t < 2; ++t) {
                int key = k0 + t * 16 + c;
                float s = sa[t][i] * kscale;
                sv[t][i] = (key <= qrow) ? s : -1e30f;
            }
            float mv = fmaxf(sv[0][i], sv[1][i]);
            mv = fmaxf(mv, __shfl_xor(mv, 1));
            mv = fmaxf(mv, __shfl_xor(mv, 2));
            mv = fmaxf(mv, __shfl_xor(mv, 4));
            mv = fmaxf(mv, __shfl_xor(mv, 8));

            float mnew = fmaxf(m_run[i], mv);
            float corr = exp2f(m_run[i] - mnew);
            m_run[i] = mnew;
            float p0 = exp2f(sv[0][i] - mnew);
            float p1 = exp2f(sv[1][i] - mnew);
            float ps = p0 + p1;
            ps += __shfl_xor(ps, 1);
            ps += __shfl_xor(ps, 2);
            ps += __shfl_xor(ps, 4);
            ps += __shfl_xor(ps, 8);
            l_run[i] = l_run[i] * corr + ps;
            #pragma unroll
            for (int dt = 0; dt < 16; ++dt) o[dt][i] *= corr;

            Plds[wid][g * 4 + i][c]      = f2bf(p0);
            Plds[wid][g * 4 + i][16 + c] = f2bf(p1);
        }

        bf16x8 pa = *(const bf16x8*)&Plds[wid][c][g * 8];

        #pragma unroll
        for (int dt = 0; dt < 16; ++dt) {
            const unsigned short* vp = vbase + (size_t)(dt * 16 + c) * SEQ + k0 + g * 8;
            bf16x8 vf = *(const bf16x8*)vp;
            o[dt] = __builtin_amdgcn_mfma_f32_16x16x32_bf16(pa, vf, o[dt], 0, 0, 0);
        }
    }

    if (split == 1) {
        #pragma unroll
        for (int i = 0; i < 4; ++i) {
            float inv = 1.0f / l_run[i];
            int row = q0 + g * 4 + i;
            #pragma unroll
            for (int dt = 0; dt < 16; ++dt) {
                int col = dt * 16 + c;
                size_t idx = ((size_t)b * SEQ + row) * DIM + col;
                float r = o[dt][i] * inv + xres[idx];
                xout[idx] = r;
                xb_next[idx] = f2bf(r);
            }
        }
    } else {
        int gq = b * QT + qtile;
        size_t pbase = ((size_t)(s_idx * PB + gq)) * 16;
        #pragma unroll
        for (int i = 0; i < 4; ++i) {
            int row_r = g * 4 + i;
            if (c == 0) {
                partM[pbase + row_r] = m_run[i];
                partL[pbase + row_r] = l_run[i];
            }
            #pragma unroll
            for (int dt = 0; dt < 16; ++dt) {
                partO[(pbase + row_r) * DIM + dt * 16 + c] = o[dt][i];
            }
        }
    }
}

// ---------------- split-KV combine + residual ----------------
__global__ __launch_bounds__(256) void combine_kernel(const float* __restrict__ partO,
                                                      const float* __restrict__ partM,
                                                      const float* __restrict__ partL,
                                                      const float* __restrict__ xres,
                                                      float* __restrict__ xout,
                                                      unsigned short* __restrict__ xb_next,
                                                      int split) {
    int q = blockIdx.x, b = blockIdx.y;
    int gq = b * QT + q;
    int t = threadIdx.x;
    int row = t >> 4, ci = t & 15;

    float mv[4];
    float M = -1e30f;
    for (int s = 0; s < split; ++s) {
        mv[s] = partM[((size_t)(s * PB + gq)) * 16 + row];
        M = fmaxf(M, mv[s]);
    }
    float L = 0.f;
    for (int s = 0; s < split; ++s)
        L += partL[((size_t)(s * PB + gq)) * 16 + row] * exp2f(mv[s] - M);
    float invL = 1.0f / L;

    float acc[16] = {};
    for (int s = 0; s < split; ++s) {
        float w = exp2f(mv[s] - M);
        if (w > 0.f) {
            const float* po = partO + (((size_t)(s * PB + gq)) * 16 + row) * DIM + ci * 16;
            #pragma unroll
            for (int j = 0; j < 4; ++j) {
                float4 v = *(const float4*)(po + j * 4);
                acc[j * 4 + 0] += w * v.x;
                acc[j * 4 + 1] += w * v.y;
                acc[j * 4 + 2] += w * v.z;
                acc[j * 4 + 3] += w * v.w;
            }
        }
    }

    size_t base = ((size_t)(b * SEQ + q * 16 + row)) * DIM + ci * 16;
    #pragma unroll
    for (int j = 0; j < 4; ++j) {
        float4 r = *(const float4*)(xres + base + j * 4);
        float4 ov;
        ov.x = acc[j * 4 + 0] * invL + r.x;
        ov.y = acc[j * 4 + 1] * invL + r.y;
        ov.z = acc[j * 4 + 2] * invL + r.z;
        ov.w = acc[j * 4 + 3] * invL + r.w;
        *(float4*)(xout + base + j * 4) = ov;
        ushort4 hb = {f2bf(ov.x), f2bf(ov.y), f2bf(ov.z), f2bf(ov.w)};
        *(ushort4*)(xb_next + base + j * 4) = hb;
    }
}

// ---------------- launch ----------------
extern "C" void kernel_launch(void* const* d_in, const int* in_sizes, int n_in,
                              void* d_out, int out_size, void* d_ws, size_t ws_size,
                              hipStream_t stream) {
    const float* x_in = (const float*)d_in[0];
    const float* Wq   = (const float*)d_in[1];
    const float* bq   = (const float*)d_in[2];
    const float* Wk   = (const float*)d_in[3];
    const float* bk   = (const float*)d_in[4];
    const float* Wv   = (const float*)d_in[5];
    const float* bv   = (const float*)d_in[6];
    float* xout = (float*)d_out;

    const size_t SD = (size_t)BATCH * SEQ * DIM;
    const size_t WL = (size_t)LAYERS * DIM * DIM;
    unsigned short* qb  = (unsigned short*)d_ws;
    unsigned short* kbf = qb  + SD;
    unsigned short* vt  = kbf + SD;
    unsigned short* xb  = vt  + SD;
    unsigned short* Wqb = xb  + SD;
    unsigned short* Wkb = Wqb + WL;
    unsigned short* Wvb = Wkb + WL;
    size_t base_bytes = (4 * SD + 3 * WL) * sizeof(unsigned short);   // ~35.1 MB

    // pick the largest KV split whose partials fit in the remaining workspace
    int split = 1;
    for (int s = 4; s >= 2; s >>= 1) {
        size_t need = base_bytes + (size_t)s * PB * 16 * (DIM + 2) * sizeof(float);
        if (ws_size >= need) { split = s; break; }
    }
    float* partO = (float*)((char*)d_ws + base_bytes);
    float* partM = partO + (size_t)split * PB * 16 * DIM;
    float* partL = partM + (size_t)split * PB * 16;

    // weights -> bf16 (once per call)
    {
        int n = (int)WL;
        int blocks = (n / 4 + 255) / 256;
        cvt_kernel<<<blocks, 256, 0, stream>>>(Wq, Wqb, n);
        cvt_kernel<<<blocks, 256, 0, stream>>>(Wk, Wkb, n);
        cvt_kernel<<<blocks, 256, 0, stream>>>(Wv, Wvb, n);
    }
    // x -> bf16 (layer 0 only; later layers produced by attn/combine epilogue)
    {
        int n = (int)SD;
        int blocks = (n / 4 + 255) / 256;
        cvt_kernel<<<blocks, 256, 0, stream>>>(x_in, xb, n);
    }

    dim3 pgrid(BATCH * SEQ / 64, DIM / 64, 3), pblk(256);
    dim3 agrid(64, split, BATCH), ablk(256);
    dim3 cgrid(QT, BATCH), cblk(256);

    for (int l = 0; l < LAYERS; ++l) {
        const float* xcur = (l == 0) ? x_in : xout;
        size_t wl_off = (size_t)l * DIM * DIM;
        projqkv_kernel<<<pgrid, pblk, 0, stream>>>(xb, Wqb + wl_off, Wkb + wl_off, Wvb + wl_off,
                                                   bq + l * DIM, bk + l * DIM, bv + l * DIM,
                                                   qb, kbf, vt);
        attn_kernel<<<agrid, ablk, 0, stream>>>(qb, kbf, vt, xcur, xout, xb,
                                                partO, partM, partL, split);
        if (split > 1)
            combine_kernel<<<cgrid, cblk, 0, stream>>>(partO, partM, partL, xcur, xout, xb, split);
    }
}

// Round 3
// 846.832 us; speedup vs baseline: 2.8121x; 1.8702x over previous
//
#include <hip/hip_runtime.h>
#include <hip/hip_bf16.h>

#define SEQ 4096
#define DIM 256
#define BATCH 4
#define LAYERS 4
#define QT (SEQ / 16)        // 256 q-tiles per batch
#define PB (BATCH * QT)      // 1024 q-tiles total
#define KVB 32               // keys per KV step

typedef __attribute__((ext_vector_type(8))) short bf16x8;
typedef __attribute__((ext_vector_type(4))) float f32x4;

__device__ __forceinline__ unsigned short f2bf(float f) {
    union { float f; unsigned u; } v; v.f = f;
    unsigned r = v.u + 0x7fff + ((v.u >> 16) & 1);   // round-to-nearest-even
    return (unsigned short)(r >> 16);
}

// async global->LDS, 16B per lane; LDS dest = wave-uniform base + lane*16
__device__ __forceinline__ void gload_lds16(const void* g, void* l) {
    __builtin_amdgcn_global_load_lds(
        (const __attribute__((address_space(1))) unsigned int*)g,
        (__attribute__((address_space(3))) unsigned int*)l, 16, 0, 0);
}

// ---------------- fp32 -> bf16 conversion (vectorized) ----------------
__global__ __launch_bounds__(256) void cvt_kernel(const float* __restrict__ in,
                                                  unsigned short* __restrict__ out,
                                                  int n) {
    int i = (blockIdx.x * blockDim.x + threadIdx.x) * 4;
    if (i + 3 < n) {
        float4 v = *(const float4*)(in + i);
        ushort4 o = {f2bf(v.x), f2bf(v.y), f2bf(v.z), f2bf(v.w)};
        *(ushort4*)(out + i) = o;
    }
}

// ---------------- fused QKV projection: out_z = x @ W_z^T + b_z ----------------
__global__ __launch_bounds__(256) void projqkv_kernel(const unsigned short* __restrict__ xb,
                                                      const unsigned short* __restrict__ Wq,
                                                      const unsigned short* __restrict__ Wk,
                                                      const unsigned short* __restrict__ Wv,
                                                      const float* __restrict__ bq,
                                                      const float* __restrict__ bk,
                                                      const float* __restrict__ bv,
                                                      unsigned short* __restrict__ outq,
                                                      unsigned short* __restrict__ outk,
                                                      unsigned short* __restrict__ outv) {
    int z = blockIdx.z;
    const unsigned short* Wb = (z == 0) ? Wq : (z == 1) ? Wk : Wv;
    const float* bias        = (z == 0) ? bq : (z == 1) ? bk : bv;
    unsigned short* out      = (z == 0) ? outq : (z == 1) ? outk : outv;
    int vt_mode = (z == 2);

    int lane = threadIdx.x & 63;
    int wid  = threadIdx.x >> 6;
    int c = lane & 15, g = lane >> 4;
    int m0 = blockIdx.x * 64 + wid * 16;
    int n0 = blockIdx.y * 64;

    f32x4 acc[4] = {};
    const unsigned short* xrow = xb + (size_t)(m0 + c) * DIM + g * 8;

    #pragma unroll
    for (int s = 0; s < 8; ++s) {
        bf16x8 a = *(const bf16x8*)(xrow + s * 32);
        #pragma unroll
        for (int nt = 0; nt < 4; ++nt) {
            const unsigned short* wp = Wb + (size_t)(n0 + nt * 16 + c) * DIM + s * 32 + g * 8;
            bf16x8 bf = *(const bf16x8*)wp;
            acc[nt] = __builtin_amdgcn_mfma_f32_16x16x32_bf16(a, bf, acc[nt], 0, 0, 0);
        }
    }

    #pragma unroll
    for (int nt = 0; nt < 4; ++nt) {
        int col = n0 + nt * 16 + c;
        float bv_ = bias[col];
        #pragma unroll
        for (int i = 0; i < 4; ++i) {
            int row = m0 + g * 4 + i;
            unsigned short h = f2bf(acc[nt][i] + bv_);
            if (!vt_mode) {
                out[(size_t)row * DIM + col] = h;
            } else {
                int b = row >> 12;
                int sidx = row & (SEQ - 1);
                out[((size_t)b * DIM + col) * SEQ + sidx] = h;
            }
        }
    }
}

// ---------------- causal flash attention (split-KV, LDS-staged K/V) ----------------
// qb,kb: [B][S][D] bf16 ; vt: [B][D][S] bf16
// Block = 4 waves = 4 consecutive q-tiles; two passes (low quad + complementary high quad).
// K/V tiles double-buffered in LDS via global_load_lds (shared by all 4 waves).
__global__ __launch_bounds__(256, 2) void attn_kernel(const unsigned short* __restrict__ qb,
                                                      const unsigned short* __restrict__ kb,
                                                      const unsigned short* __restrict__ vt,
                                                      const float* __restrict__ xres,
                                                      float* __restrict__ xout,
                                                      unsigned short* __restrict__ xb_next,
                                                      float* __restrict__ partO,
                                                      float* __restrict__ partM,
                                                      float* __restrict__ partL,
                                                      int split) {
    // K: [2][32 rows][256], row k stores global 16B-slot (sl ^ (k&7)) at slot sl (XOR swizzle)
    // V: [2] chunk-major: byte off = ch*4096 + d*16  (ch = 8-key chunk, d = 0..255)
    __shared__ unsigned short Klds[2][32 * 256];
    __shared__ unsigned short Vlds[2][32 * 256];
    __shared__ unsigned short Plds[4][16 * 32];

    int tid  = threadIdx.x;
    int lane = tid & 63, wid = tid >> 6;
    int c = lane & 15, g = lane >> 4;
    int s_idx = blockIdx.y;
    int b = blockIdx.z;

    const unsigned short* kbase = kb + (size_t)b * SEQ * DIM;
    const unsigned short* vbase = vt + (size_t)b * DIM * SEQ;
    const float kscale = (1.0f / 16.0f) * 1.44269504f;   // 1/sqrt(D) * log2(e)

    auto STAGE = [&](int bf, int k0) {
        #pragma unroll
        for (int r = 0; r < 4; ++r) {
            // K tile: LDS byte L = r*4096 + tid*16 -> row k = r*8 + tid/32, slot sl = tid&31
            int k  = r * 8 + (tid >> 5);
            int sl = tid & 31;
            const unsigned short* ks = kbase + (size_t)(k0 + k) * DIM + ((sl ^ (k & 7)) << 3);
            gload_lds16(ks, (char*)&Klds[bf][0] + r * 4096 + wid * 1024);
            // V tile: LDS byte L = r*4096 + tid*16 -> ch = r, d = tid
            const unsigned short* vs = vbase + (size_t)tid * SEQ + k0 + r * 8;
            gload_lds16(vs, (char*)&Vlds[bf][0] + r * 4096 + wid * 1024);
        }
    };

    for (int pass_ = 0; pass_ < 2; ++pass_) {
        int quad  = pass_ ? (63 - (int)blockIdx.x) : (int)blockIdx.x;
        int qtile = quad * 4 + wid;
        int q0 = qtile * 16;
        int nsteps_own = (q0 + 47) >> 5;
        int nsteps_max = (quad * 64 + 95) >> 5;
        int cnt_own = (nsteps_own > s_idx) ? (nsteps_own - s_idx + split - 1) / split : 0;
        int cnt_max = (nsteps_max > s_idx) ? (nsteps_max - s_idx + split - 1) / split : 0;

        // hoist Q fragments
        bf16x8 qf[8];
        const unsigned short* qp = qb + ((size_t)(b * SEQ + q0 + c)) * DIM + g * 8;
        #pragma unroll
        for (int s = 0; s < 8; ++s) qf[s] = *(const bf16x8*)(qp + s * 32);

        f32x4 o[16] = {};
        float m_run[4], l_run[4];
        #pragma unroll
        for (int i = 0; i < 4; ++i) { m_run[i] = -1e30f; l_run[i] = 0.f; }

        int buf = 0;
        if (cnt_max > 0) {
            STAGE(0, s_idx * KVB);
            __syncthreads();

            for (int j = 0; j < cnt_max; ++j) {
                if (j + 1 < cnt_max) STAGE(buf ^ 1, (s_idx + (j + 1) * split) * KVB);

                if (j < cnt_own) {
                    int k0 = (s_idx + j * split) * KVB;

                    // ---- QK^T from LDS ----
                    f32x4 sa[2] = {};
                    const unsigned short* Kb = &Klds[buf][0];
                    #pragma unroll
                    for (int t = 0; t < 2; ++t) {
                        int krow = t * 16 + c;
                        #pragma unroll
                        for (int s = 0; s < 8; ++s) {
                            int off = krow * 256 + (((s * 4 + g) ^ (c & 7)) << 3);
                            bf16x8 kf = *(const bf16x8*)(Kb + off);
                            sa[t] = __builtin_amdgcn_mfma_f32_16x16x32_bf16(qf[s], kf, sa[t], 0, 0, 0);
                        }
                    }

                    // ---- mask + scale + row max ----
                    float sv[2][4], pmax[4];
                    bool ok = true;
                    #pragma unroll
                    for (int i = 0; i < 4; ++i) {
                        int qrow = q0 + g * 4 + i;
                        #pragma unroll
                        for (int t = 0; t < 2; ++t) {
                            int key = k0 + t * 16 + c;
                            float s = sa[t][i] * kscale;
                            sv[t][i] = (key <= qrow) ? s : -1e30f;
                        }
                        float mv = fmaxf(sv[0][i], sv[1][i]);
                        mv = fmaxf(mv, __shfl_xor(mv, 1));
                        mv = fmaxf(mv, __shfl_xor(mv, 2));
                        mv = fmaxf(mv, __shfl_xor(mv, 4));
                        mv = fmaxf(mv, __shfl_xor(mv, 8));
                        pmax[i] = mv;
                        ok = ok && (mv <= m_run[i] + 8.0f);
                    }

                    // ---- defer-rescale: only rescale when max grew past THR ----
                    if (!__all(ok)) {
                        #pragma unroll
                        for (int i = 0; i < 4; ++i) {
                            float mnew = fmaxf(m_run[i], pmax[i]);
                            float corr = exp2f(m_run[i] - mnew);
                            m_run[i] = mnew;
                            l_run[i] *= corr;
                            #pragma unroll
                            for (int dt = 0; dt < 16; ++dt) o[dt][i] *= corr;
                        }
                    }

                    // ---- P = exp2(S - m), per-lane partial l ----
                    #pragma unroll
                    for (int i = 0; i < 4; ++i) {
                        float p0 = exp2f(sv[0][i] - m_run[i]);
                        float p1 = exp2f(sv[1][i] - m_run[i]);
                        l_run[i] += p0 + p1;
                        Plds[wid][(g * 4 + i) * 32 + c]      = f2bf(p0);
                        Plds[wid][(g * 4 + i) * 32 + 16 + c] = f2bf(p1);
                    }

                    // ---- O += P V from LDS ----
                    bf16x8 paf = *(const bf16x8*)&Plds[wid][c * 32 + g * 8];
                    const unsigned short* Vb = &Vlds[buf][0];
                    #pragma unroll
                    for (int dt = 0; dt < 16; ++dt) {
                        bf16x8 vf = *(const bf16x8*)(Vb + g * 2048 + (dt * 16 + c) * 8);
                        o[dt] = __builtin_amdgcn_mfma_f32_16x16x32_bf16(paf, vf, o[dt], 0, 0, 0);
                    }
                }

                __syncthreads();   // drains stage vmem (had full compute phase to land)
                buf ^= 1;
            }
        }

        // ---- epilogue: reduce per-lane l partials across the 16-lane row ----
        #pragma unroll
        for (int i = 0; i < 4; ++i) {
            float l = l_run[i];
            l += __shfl_xor(l, 1);
            l += __shfl_xor(l, 2);
            l += __shfl_xor(l, 4);
            l += __shfl_xor(l, 8);
            l_run[i] = l;
        }

        if (split == 1) {
            #pragma unroll
            for (int i = 0; i < 4; ++i) {
                float inv = 1.0f / l_run[i];
                int row = q0 + g * 4 + i;
                #pragma unroll
                for (int dt = 0; dt < 16; ++dt) {
                    int col = dt * 16 + c;
                    size_t idx = ((size_t)b * SEQ + row) * DIM + col;
                    float r = o[dt][i] * inv + xres[idx];
                    xout[idx] = r;
                    xb_next[idx] = f2bf(r);
                }
            }
        } else {
            int gq = b * QT + qtile;
            size_t pbase = ((size_t)(s_idx * PB + gq)) * 16;
            #pragma unroll
            for (int i = 0; i < 4; ++i) {
                int row_r = g * 4 + i;
                if (c == 0) {
                    partM[pbase + row_r] = m_run[i];
                    partL[pbase + row_r] = l_run[i];
                }
                #pragma unroll
                for (int dt = 0; dt < 16; ++dt) {
                    partO[(pbase + row_r) * DIM + dt * 16 + c] = o[dt][i];
                }
            }
        }
    }
}

// ---------------- split-KV combine + residual ----------------
__global__ __launch_bounds__(256) void combine_kernel(const float* __restrict__ partO,
                                                      const float* __restrict__ partM,
                                                      const float* __restrict__ partL,
                                                      const float* __restrict__ xres,
                                                      float* __restrict__ xout,
                                                      unsigned short* __restrict__ xb_next,
                                                      int split) {
    int q = blockIdx.x, b = blockIdx.y;
    int gq = b * QT + q;
    int t = threadIdx.x;
    int row = t >> 4, ci = t & 15;

    float mv[4];
    float M = -1e30f;
    for (int s = 0; s < split; ++s) {
        mv[s] = partM[((size_t)(s * PB + gq)) * 16 + row];
        M = fmaxf(M, mv[s]);
    }
    float L = 0.f;
    for (int s = 0; s < split; ++s)
        L += partL[((size_t)(s * PB + gq)) * 16 + row] * exp2f(mv[s] - M);
    float invL = 1.0f / L;

    float acc[16] = {};
    for (int s = 0; s < split; ++s) {
        float w = exp2f(mv[s] - M);
        if (w > 0.f) {
            const float* po = partO + (((size_t)(s * PB + gq)) * 16 + row) * DIM + ci * 16;
            #pragma unroll
            for (int j = 0; j < 4; ++j) {
                float4 v = *(const float4*)(po + j * 4);
                acc[j * 4 + 0] += w * v.x;
                acc[j * 4 + 1] += w * v.y;
                acc[j * 4 + 2] += w * v.z;
                acc[j * 4 + 3] += w * v.w;
            }
        }
    }

    size_t base = ((size_t)(b * SEQ + q * 16 + row)) * DIM + ci * 16;
    #pragma unroll
    for (int j = 0; j < 4; ++j) {
        float4 r = *(const float4*)(xres + base + j * 4);
        float4 ov;
        ov.x = acc[j * 4 + 0] * invL + r.x;
        ov.y = acc[j * 4 + 1] * invL + r.y;
        ov.z = acc[j * 4 + 2] * invL + r.z;
        ov.w = acc[j * 4 + 3] * invL + r.w;
        *(float4*)(xout + base + j * 4) = ov;
        ushort4 hb = {f2bf(ov.x), f2bf(ov.y), f2bf(ov.z), f2bf(ov.w)};
        *(ushort4*)(xb_next + base + j * 4) = hb;
    }
}

// ---------------- launch ----------------
extern "C" void kernel_launch(void* const* d_in, const int* in_sizes, int n_in,
                              void* d_out, int out_size, void* d_ws, size_t ws_size,
                              hipStream_t stream) {
    const float* x_in = (const float*)d_in[0];
    const float* Wq   = (const float*)d_in[1];
    const float* bq   = (const float*)d_in[2];
    const float* Wk   = (const float*)d_in[3];
    const float* bk   = (const float*)d_in[4];
    const float* Wv   = (const float*)d_in[5];
    const float* bv   = (const float*)d_in[6];
    float* xout = (float*)d_out;

    const size_t SD = (size_t)BATCH * SEQ * DIM;
    const size_t WL = (size_t)LAYERS * DIM * DIM;
    unsigned short* qb  = (unsigned short*)d_ws;
    unsigned short* kbf = qb  + SD;
    unsigned short* vt  = kbf + SD;
    unsigned short* xb  = vt  + SD;
    unsigned short* Wqb = xb  + SD;
    unsigned short* Wkb = Wqb + WL;
    unsigned short* Wvb = Wkb + WL;
    size_t base_bytes = (4 * SD + 3 * WL) * sizeof(unsigned short);   // ~35.1 MB

    int split = 1;
    for (int s = 4; s >= 2; s >>= 1) {
        size_t need = base_bytes + (size_t)s * PB * 16 * (DIM + 2) * sizeof(float);
        if (ws_size >= need) { split = s; break; }
    }
    float* partO = (float*)((char*)d_ws + base_bytes);
    float* partM = partO + (size_t)split * PB * 16 * DIM;
    float* partL = partM + (size_t)split * PB * 16;

    {
        int n = (int)WL;
        int blocks = (n / 4 + 255) / 256;
        cvt_kernel<<<blocks, 256, 0, stream>>>(Wq, Wqb, n);
        cvt_kernel<<<blocks, 256, 0, stream>>>(Wk, Wkb, n);
        cvt_kernel<<<blocks, 256, 0, stream>>>(Wv, Wvb, n);
    }
    {
        int n = (int)SD;
        int blocks = (n / 4 + 255) / 256;
        cvt_kernel<<<blocks, 256, 0, stream>>>(x_in, xb, n);
    }

    dim3 pgrid(BATCH * SEQ / 64, DIM / 64, 3), pblk(256);
    dim3 agrid(32, split, BATCH), ablk(256);
    dim3 cgrid(QT, BATCH), cblk(256);

    for (int l = 0; l < LAYERS; ++l) {
        const float* xcur = (l == 0) ? x_in : xout;
        size_t wl_off = (size_t)l * DIM * DIM;
        projqkv_kernel<<<pgrid, pblk, 0, stream>>>(xb, Wqb + wl_off, Wkb + wl_off, Wvb + wl_off,
                                                   bq + l * DIM, bk + l * DIM, bv + l * DIM,
                                                   qb, kbf, vt);
        attn_kernel<<<agrid, ablk, 0, stream>>>(qb, kbf, vt, xcur, xout, xb,
                                                partO, partM, partL, split);
        if (split > 1)
            combine_kernel<<<cgrid, cblk, 0, stream>>>(partO, partM, partL, xcur, xout, xb, split);
    }
}

// Round 4
// 748.650 us; speedup vs baseline: 3.1809x; 1.1311x over previous
//
#include <hip/hip_runtime.h>
#include <hip/hip_bf16.h>

#define SEQ 4096
#define DIM 256
#define BATCH 4
#define LAYERS 4
#define QT (SEQ / 16)        // 256 q-tiles per batch
#define PB (BATCH * QT)      // 1024 q-tiles total
#define KVB 32               // keys per KV step

typedef __attribute__((ext_vector_type(8))) short bf16x8;
typedef __attribute__((ext_vector_type(4))) float f32x4;

__device__ __forceinline__ unsigned short f2bf(float f) {
    union { float f; unsigned u; } v; v.f = f;
    unsigned r = v.u + 0x7fff + ((v.u >> 16) & 1);   // round-to-nearest-even
    return (unsigned short)(r >> 16);
}

__device__ __forceinline__ unsigned cvt_pk_bf16(float lo, float hi) {
    unsigned r;
    asm volatile("v_cvt_pk_bf16_f32 %0, %1, %2" : "=v"(r) : "v"(lo), "v"(hi));
    return r;
}

__device__ __forceinline__ float bperm_f(float v, int srclane) {
    return __int_as_float(__builtin_amdgcn_ds_bpermute(srclane << 2, __float_as_int(v)));
}

// async global->LDS, 16B per lane; LDS dest = wave-uniform base + lane*16
__device__ __forceinline__ void gload_lds16(const void* g, void* l) {
    __builtin_amdgcn_global_load_lds(
        (const __attribute__((address_space(1))) unsigned int*)g,
        (__attribute__((address_space(3))) unsigned int*)l, 16, 0, 0);
}

// ---------------- fp32 -> bf16 conversion (vectorized) ----------------
__global__ __launch_bounds__(256) void cvt_kernel(const float* __restrict__ in,
                                                  unsigned short* __restrict__ out,
                                                  int n) {
    int i = (blockIdx.x * blockDim.x + threadIdx.x) * 4;
    if (i + 3 < n) {
        float4 v = *(const float4*)(in + i);
        ushort4 o = {f2bf(v.x), f2bf(v.y), f2bf(v.z), f2bf(v.w)};
        *(ushort4*)(out + i) = o;
    }
}

// ---------------- fused QKV projection: out_z = x @ W_z^T + b_z ----------------
__global__ __launch_bounds__(256) void projqkv_kernel(const unsigned short* __restrict__ xb,
                                                      const unsigned short* __restrict__ Wq,
                                                      const unsigned short* __restrict__ Wk,
                                                      const unsigned short* __restrict__ Wv,
                                                      const float* __restrict__ bq,
                                                      const float* __restrict__ bk,
                                                      const float* __restrict__ bv,
                                                      unsigned short* __restrict__ outq,
                                                      unsigned short* __restrict__ outk,
                                                      unsigned short* __restrict__ outv) {
    int z = blockIdx.z;
    const unsigned short* Wb = (z == 0) ? Wq : (z == 1) ? Wk : Wv;
    const float* bias        = (z == 0) ? bq : (z == 1) ? bk : bv;
    unsigned short* out      = (z == 0) ? outq : (z == 1) ? outk : outv;
    int vt_mode = (z == 2);

    int lane = threadIdx.x & 63;
    int wid  = threadIdx.x >> 6;
    int c = lane & 15, g = lane >> 4;
    int m0 = blockIdx.x * 64 + wid * 16;
    int n0 = blockIdx.y * 64;

    f32x4 acc[4] = {};
    const unsigned short* xrow = xb + (size_t)(m0 + c) * DIM + g * 8;

    #pragma unroll
    for (int s = 0; s < 8; ++s) {
        bf16x8 a = *(const bf16x8*)(xrow + s * 32);
        #pragma unroll
        for (int nt = 0; nt < 4; ++nt) {
            const unsigned short* wp = Wb + (size_t)(n0 + nt * 16 + c) * DIM + s * 32 + g * 8;
            bf16x8 bf = *(const bf16x8*)wp;
            acc[nt] = __builtin_amdgcn_mfma_f32_16x16x32_bf16(a, bf, acc[nt], 0, 0, 0);
        }
    }

    #pragma unroll
    for (int nt = 0; nt < 4; ++nt) {
        int col = n0 + nt * 16 + c;
        float bv_ = bias[col];
        #pragma unroll
        for (int i = 0; i < 4; ++i) {
            int row = m0 + g * 4 + i;
            unsigned short h = f2bf(acc[nt][i] + bv_);
            if (!vt_mode) {
                out[(size_t)row * DIM + col] = h;
            } else {
                int b = row >> 12;
                int sidx = row & (SEQ - 1);
                out[((size_t)b * DIM + col) * SEQ + sidx] = h;
            }
        }
    }
}

// ---------------- causal flash attention (split-KV, LDS K/V, lane-local softmax) ----------------
// qb,kb: [B][S][D] bf16 ; vt: [B][D][S] bf16
// Swapped QK^T (mfma(K,Q)) -> each lane owns one q-row's scores; softmax is
// in-register (2 shfls for max, 0 for l). P repacked via cvt_pk + tiny swizzled LDS patch.
__global__ __launch_bounds__(256, 2) void attn_kernel(const unsigned short* __restrict__ qb,
                                                      const unsigned short* __restrict__ kb,
                                                      const unsigned short* __restrict__ vt,
                                                      const float* __restrict__ xres,
                                                      float* __restrict__ xout,
                                                      unsigned short* __restrict__ xb_next,
                                                      float* __restrict__ partO,
                                                      float* __restrict__ partM,
                                                      float* __restrict__ partL,
                                                      int split) {
    // K: [2][32 rows][256], row k stores global 16B-slot (sl ^ (k&7)) at slot sl (XOR swizzle)
    // V: [2] chunk-major: byte off = ch*4096 + d*16  (ch = 8-key chunk, d = 0..255)
    __shared__ unsigned short Klds[2][32 * 256];
    __shared__ unsigned short Vlds[2][32 * 256];
    __shared__ unsigned int   Plds[4][256];     // per-wave 1KB P patch, slot-XOR swizzled

    int tid  = threadIdx.x;
    int lane = tid & 63, wid = tid >> 6;
    int c = lane & 15, g = lane >> 4;

    // XCD-locality decode: batch = x>>1 -> round-robin dispatch keeps each
    // batch's KV on ~2 XCD L2s.  k2 enumerates (quad, split-slice).
    int b  = blockIdx.x >> 1;
    int k2 = blockIdx.y * 2 + (blockIdx.x & 1);
    int quad0 = k2 & 31;
    int s_idx = k2 >> 5;

    const unsigned short* kbase = kb + (size_t)b * SEQ * DIM;
    const unsigned short* vbase = vt + (size_t)b * DIM * SEQ;
    const float kscale = (1.0f / 16.0f) * 1.44269504f;   // 1/sqrt(D) * log2(e)

    auto STAGE = [&](int bf, int k0) {
        #pragma unroll
        for (int r = 0; r < 4; ++r) {
            int k  = r * 8 + (tid >> 5);
            int sl = tid & 31;
            const unsigned short* ks = kbase + (size_t)(k0 + k) * DIM + ((sl ^ (k & 7)) << 3);
            gload_lds16(ks, (char*)&Klds[bf][0] + r * 4096 + wid * 1024);
            const unsigned short* vs = vbase + (size_t)tid * SEQ + k0 + r * 8;
            gload_lds16(vs, (char*)&Vlds[bf][0] + r * 4096 + wid * 1024);
        }
    };

    for (int pass_ = 0; pass_ < 2; ++pass_) {
        int quad  = pass_ ? (63 - quad0) : quad0;
        int qtile = quad * 4 + wid;
        int q0 = qtile * 16;
        int nsteps_own = (q0 + 47) >> 5;
        int nsteps_max = (quad * 64 + 95) >> 5;
        int cnt_own = (nsteps_own > s_idx) ? (nsteps_own - s_idx + split - 1) / split : 0;
        int cnt_max = (nsteps_max > s_idx) ? (nsteps_max - s_idx + split - 1) / split : 0;

        bf16x8 qf[8];
        const unsigned short* qp = qb + ((size_t)(b * SEQ + q0 + c)) * DIM + g * 8;
        #pragma unroll
        for (int s = 0; s < 8; ++s) qf[s] = *(const bf16x8*)(qp + s * 32);

        f32x4 o[16] = {};
        float m_run = -1e30f, l_run = 0.f;    // per-lane scalars, q = q0 + c

        int buf = 0;
        if (cnt_max > 0) {
            STAGE(0, s_idx * KVB);
            __syncthreads();

            for (int j = 0; j < cnt_max; ++j) {
                if (j + 1 < cnt_max) STAGE(buf ^ 1, (s_idx + (j + 1) * split) * KVB);

                if (j < cnt_own) {
                    int k0 = (s_idx + j * split) * KVB;

                    // ---- swapped QK^T: S^T[k][q], lane holds 8 k-scores for q=q0+c ----
                    f32x4 sa[2] = {};
                    const unsigned short* Kb = &Klds[buf][0];
                    #pragma unroll
                    for (int t = 0; t < 2; ++t) {
                        int krow = t * 16 + c;
                        #pragma unroll
                        for (int s = 0; s < 8; ++s) {
                            int off = krow * 256 + (((s * 4 + g) ^ (c & 7)) << 3);
                            bf16x8 kf = *(const bf16x8*)(Kb + off);
                            sa[t] = __builtin_amdgcn_mfma_f32_16x16x32_bf16(kf, qf[s], sa[t], 0, 0, 0);
                        }
                    }

                    // ---- mask + scale + in-register row max ----
                    int qv = q0 + c;
                    float sv[2][4];
                    float mloc = -1e30f;
                    #pragma unroll
                    for (int t = 0; t < 2; ++t)
                        #pragma unroll
                        for (int i = 0; i < 4; ++i) {
                            int key = k0 + t * 16 + g * 4 + i;
                            float s = sa[t][i] * kscale;
                            sv[t][i] = (key <= qv) ? s : -1e30f;
                            mloc = fmaxf(mloc, sv[t][i]);
                        }
                    mloc = fmaxf(mloc, __shfl_xor(mloc, 16));
                    mloc = fmaxf(mloc, __shfl_xor(mloc, 32));

                    // ---- defer-rescale (THR=8 in exp2 domain) ----
                    if (!__all(mloc <= m_run + 8.0f)) {
                        float mnew = fmaxf(m_run, mloc);
                        float corr = exp2f(m_run - mnew);
                        m_run = mnew;
                        l_run *= corr;
                        #pragma unroll
                        for (int i = 0; i < 4; ++i) {
                            float cr = bperm_f(corr, g * 4 + i);   // corr for o-row q0+g*4+i
                            #pragma unroll
                            for (int dt = 0; dt < 16; ++dt) o[dt][i] *= cr;
                        }
                    }

                    // ---- P = exp2(S - m): in-register, pack, stash to swizzled patch ----
                    #pragma unroll
                    for (int t = 0; t < 2; ++t) {
                        float p0 = exp2f(sv[t][0] - m_run);
                        float p1 = exp2f(sv[t][1] - m_run);
                        float p2 = exp2f(sv[t][2] - m_run);
                        float p3 = exp2f(sv[t][3] - m_run);
                        l_run += (p0 + p1) + (p2 + p3);
                        unsigned w0 = cvt_pk_bf16(p0, p1);
                        unsigned w1 = cvt_pk_bf16(p2, p3);
                        int base = c * 16 + (((t * 2 + (g >> 1)) ^ (c & 3)) << 2) + ((g & 1) << 1);
                        Plds[wid][base]     = w0;
                        Plds[wid][base + 1] = w1;
                    }
                    // A-frag read: row q=c, k = g*8..g*8+7 (slot-XOR inverse)
                    bf16x8 paf = *(const bf16x8*)&Plds[wid][c * 16 + ((g ^ (c & 3)) << 2)];

                    // ---- O += P V ----
                    const unsigned short* Vb = &Vlds[buf][0];
                    #pragma unroll
                    for (int dt = 0; dt < 16; ++dt) {
                        bf16x8 vf = *(const bf16x8*)(Vb + g * 2048 + (dt * 16 + c) * 8);
                        o[dt] = __builtin_amdgcn_mfma_f32_16x16x32_bf16(paf, vf, o[dt], 0, 0, 0);
                    }
                }

                __syncthreads();
                buf ^= 1;
            }
        }

        // ---- epilogue: reduce per-lane l partials across g-groups ----
        float lfull = l_run;
        lfull += __shfl_xor(lfull, 16);
        lfull += __shfl_xor(lfull, 32);

        if (split == 1) {
            float invl = 1.0f / lfull;
            float invr[4];
            #pragma unroll
            for (int i = 0; i < 4; ++i) invr[i] = bperm_f(invl, g * 4 + i);
            #pragma unroll
            for (int i = 0; i < 4; ++i) {
                int row = q0 + g * 4 + i;
                #pragma unroll
                for (int dt = 0; dt < 16; ++dt) {
                    int col = dt * 16 + c;
                    size_t idx = ((size_t)b * SEQ + row) * DIM + col;
                    float r = o[dt][i] * invr[i] + xres[idx];
                    xout[idx] = r;
                    xb_next[idx] = f2bf(r);
                }
            }
        } else {
            int gq = b * QT + qtile;
            size_t pbase = ((size_t)(s_idx * PB + gq)) * 16;
            if (g == 0) {
                partM[pbase + c] = m_run;
                partL[pbase + c] = lfull;
            }
            #pragma unroll
            for (int i = 0; i < 4; ++i) {
                int row_r = g * 4 + i;
                #pragma unroll
                for (int dt = 0; dt < 16; ++dt) {
                    partO[(pbase + row_r) * DIM + dt * 16 + c] = o[dt][i];
                }
            }
        }
    }
}

// ---------------- split-KV combine + residual ----------------
__global__ __launch_bounds__(256) void combine_kernel(const float* __restrict__ partO,
                                                      const float* __restrict__ partM,
                                                      const float* __restrict__ partL,
                                                      const float* __restrict__ xres,
                                                      float* __restrict__ xout,
                                                      unsigned short* __restrict__ xb_next,
                                                      int split) {
    int q = blockIdx.x, b = blockIdx.y;
    int gq = b * QT + q;
    int t = threadIdx.x;
    int row = t >> 4, ci = t & 15;

    float mv[4];
    float M = -1e30f;
    for (int s = 0; s < split; ++s) {
        mv[s] = partM[((size_t)(s * PB + gq)) * 16 + row];
        M = fmaxf(M, mv[s]);
    }
    float L = 0.f;
    for (int s = 0; s < split; ++s)
        L += partL[((size_t)(s * PB + gq)) * 16 + row] * exp2f(mv[s] - M);
    float invL = 1.0f / L;

    float acc[16] = {};
    for (int s = 0; s < split; ++s) {
        float w = exp2f(mv[s] - M);
        if (w > 0.f) {
            const float* po = partO + (((size_t)(s * PB + gq)) * 16 + row) * DIM + ci * 16;
            #pragma unroll
            for (int j = 0; j < 4; ++j) {
                float4 v = *(const float4*)(po + j * 4);
                acc[j * 4 + 0] += w * v.x;
                acc[j * 4 + 1] += w * v.y;
                acc[j * 4 + 2] += w * v.z;
                acc[j * 4 + 3] += w * v.w;
            }
        }
    }

    size_t base = ((size_t)(b * SEQ + q * 16 + row)) * DIM + ci * 16;
    #pragma unroll
    for (int j = 0; j < 4; ++j) {
        float4 r = *(const float4*)(xres + base + j * 4);
        float4 ov;
        ov.x = acc[j * 4 + 0] * invL + r.x;
        ov.y = acc[j * 4 + 1] * invL + r.y;
        ov.z = acc[j * 4 + 2] * invL + r.z;
        ov.w = acc[j * 4 + 3] * invL + r.w;
        *(float4*)(xout + base + j * 4) = ov;
        ushort4 hb = {f2bf(ov.x), f2bf(ov.y), f2bf(ov.z), f2bf(ov.w)};
        *(ushort4*)(xb_next + base + j * 4) = hb;
    }
}

// ---------------- launch ----------------
extern "C" void kernel_launch(void* const* d_in, const int* in_sizes, int n_in,
                              void* d_out, int out_size, void* d_ws, size_t ws_size,
                              hipStream_t stream) {
    const float* x_in = (const float*)d_in[0];
    const float* Wq   = (const float*)d_in[1];
    const float* bq   = (const float*)d_in[2];
    const float* Wk   = (const float*)d_in[3];
    const float* bk   = (const float*)d_in[4];
    const float* Wv   = (const float*)d_in[5];
    const float* bv   = (const float*)d_in[6];
    float* xout = (float*)d_out;

    const size_t SD = (size_t)BATCH * SEQ * DIM;
    const size_t WL = (size_t)LAYERS * DIM * DIM;
    unsigned short* qb  = (unsigned short*)d_ws;
    unsigned short* kbf = qb  + SD;
    unsigned short* vt  = kbf + SD;
    unsigned short* xb  = vt  + SD;
    unsigned short* Wqb = xb  + SD;
    unsigned short* Wkb = Wqb + WL;
    unsigned short* Wvb = Wkb + WL;
    size_t base_bytes = (4 * SD + 3 * WL) * sizeof(unsigned short);   // ~35.1 MB

    int split = 1;
    for (int s = 4; s >= 2; s >>= 1) {
        size_t need = base_bytes + (size_t)s * PB * 16 * (DIM + 2) * sizeof(float);
        if (ws_size >= need) { split = s; break; }
    }
    float* partO = (float*)((char*)d_ws + base_bytes);
    float* partM = partO + (size_t)split * PB * 16 * DIM;
    float* partL = partM + (size_t)split * PB * 16;

    {
        int n = (int)WL;
        int blocks = (n / 4 + 255) / 256;
        cvt_kernel<<<blocks, 256, 0, stream>>>(Wq, Wqb, n);
        cvt_kernel<<<blocks, 256, 0, stream>>>(Wk, Wkb, n);
        cvt_kernel<<<blocks, 256, 0, stream>>>(Wv, Wvb, n);
    }
    {
        int n = (int)SD;
        int blocks = (n / 4 + 255) / 256;
        cvt_kernel<<<blocks, 256, 0, stream>>>(x_in, xb, n);
    }

    dim3 pgrid(BATCH * SEQ / 64, DIM / 64, 3), pblk(256);
    dim3 agrid(2 * BATCH, 16 * split), ablk(256);
    dim3 cgrid(QT, BATCH), cblk(256);

    for (int l = 0; l < LAYERS; ++l) {
        const float* xcur = (l == 0) ? x_in : xout;
        size_t wl_off = (size_t)l * DIM * DIM;
        projqkv_kernel<<<pgrid, pblk, 0, stream>>>(xb, Wqb + wl_off, Wkb + wl_off, Wvb + wl_off,
                                                   bq + l * DIM, bk + l * DIM, bv + l * DIM,
                                                   qb, kbf, vt);
        attn_kernel<<<agrid, ablk, 0, stream>>>(qb, kbf, vt, xcur, xout, xb,
                                                partO, partM, partL, split);
        if (split > 1)
            combine_kernel<<<cgrid, cblk, 0, stream>>>(partO, partM, partL, xcur, xout, xb, split);
    }
}